// Round 1
// baseline (1143.107 us; speedup 1.0000x reference)
//
#include <hip/hip_runtime.h>
#include <math.h>

#define N_NODES 100000
#define N_EDGES 1600000
#define D 128
#define N_LAYERS 3
#define N_GRAPHS 128
#define N_TARGETS 10
#define NEG_SLOPE 0.2f
#define E_TOT (N_EDGES + N_NODES)
#define NP 391  /* ceil(N_NODES/256) */

// ---------------- CSR build ----------------
__global__ void hist_kernel(const int* __restrict__ dst, int* __restrict__ deg) {
    int i = blockIdx.x * blockDim.x + threadIdx.x;
    if (i >= E_TOT) return;
    int d = (i < N_EDGES) ? dst[i] : (i - N_EDGES);
    atomicAdd(&deg[d], 1);
}

__global__ void scan1_kernel(const int* __restrict__ deg, int* __restrict__ off,
                             int* __restrict__ partials) {
    __shared__ int s[256];
    int t = threadIdx.x;
    int i = blockIdx.x * 256 + t;
    int v = (i < N_NODES) ? deg[i] : 0;
    s[t] = v;
    __syncthreads();
    for (int o = 1; o < 256; o <<= 1) {
        int x = (t >= o) ? s[t - o] : 0;
        __syncthreads();
        s[t] += x;
        __syncthreads();
    }
    if (i < N_NODES) off[i + 1] = s[t];
    if (t == 255) partials[blockIdx.x] = s[255];
}

__global__ void scan2_kernel(int* __restrict__ partials) {
    __shared__ int s[512];
    int t = threadIdx.x;
    s[t] = (t < NP) ? partials[t] : 0;
    __syncthreads();
    for (int o = 1; o < 512; o <<= 1) {
        int x = (t >= o) ? s[t - o] : 0;
        __syncthreads();
        s[t] += x;
        __syncthreads();
    }
    if (t < NP) partials[t] = s[t];
}

__global__ void scan3_kernel(int* __restrict__ off, const int* __restrict__ partials) {
    int i = blockIdx.x * 256 + threadIdx.x;
    if (i == 0) off[0] = 0;
    if (i < N_NODES) {
        int b = i >> 8;
        if (b > 0) off[i + 1] += partials[b - 1];
    }
}

__global__ void scatter_kernel(const int* __restrict__ src, const int* __restrict__ dst,
                               const int* __restrict__ off, int* __restrict__ cursor,
                               int* __restrict__ csr_src) {
    int i = blockIdx.x * blockDim.x + threadIdx.x;
    if (i >= E_TOT) return;
    int s, d;
    if (i < N_EDGES) { s = src[i]; d = dst[i]; } else { s = d = i - N_EDGES; }
    int pos = off[d] + atomicAdd(&cursor[d], 1);
    csr_src[pos] = s;
}

// ---------------- GEMM: H = X @ W, als = H.a_src, ald = H.a_dst ----------------
__global__ __launch_bounds__(512) void gemm_kernel(
        const float* __restrict__ X, const float* __restrict__ Wl,
        const float* __restrict__ asr, const float* __restrict__ ads,
        float* __restrict__ H, float* __restrict__ als, float* __restrict__ ald) {
    __shared__ float xs[128][132];   // +4 pad: rg-stride 528 floats -> 2-way max (free)
    __shared__ float ws[128][128];
    int tid = threadIdx.x;
    int row0 = blockIdx.x * 128;

    // load W (16384 floats, 32/thread as float4)
    for (int i = 0; i < 8; ++i) {
        int idx = (i * 512 + tid) * 4;
        int r = idx >> 7, c = idx & 127;
        *(float4*)&ws[r][c] = *(const float4*)&Wl[idx];
    }
    // load X tile (guarded)
    for (int i = 0; i < 8; ++i) {
        int idx = (i * 512 + tid) * 4;
        int r = idx >> 7, c = idx & 127;
        int row = row0 + r;
        float4 v = make_float4(0.f, 0.f, 0.f, 0.f);
        if (row < N_NODES) v = *(const float4*)&X[(size_t)row * D + c];
        *(float4*)&xs[r][c] = v;
    }
    __syncthreads();

    int cg = tid & 15;        // 16 col-groups of 8 cols
    int rg = tid >> 4;        // 32 row-groups of 4 rows
    int c0 = cg * 8;
    float acc[4][8];
    #pragma unroll
    for (int i = 0; i < 4; ++i)
        #pragma unroll
        for (int j = 0; j < 8; ++j) acc[i][j] = 0.f;

    #pragma unroll 4
    for (int k = 0; k < 128; ++k) {
        float4 wa = *(const float4*)&ws[k][c0];
        float4 wb = *(const float4*)&ws[k][c0 + 4];
        #pragma unroll
        for (int i = 0; i < 4; ++i) {
            float xv = xs[rg * 4 + i][k];
            acc[i][0] += xv * wa.x; acc[i][1] += xv * wa.y;
            acc[i][2] += xv * wa.z; acc[i][3] += xv * wa.w;
            acc[i][4] += xv * wb.x; acc[i][5] += xv * wb.y;
            acc[i][6] += xv * wb.z; acc[i][7] += xv * wb.w;
        }
    }

    float asv[8], adv[8];
    *(float4*)&asv[0] = *(const float4*)&asr[c0];
    *(float4*)&asv[4] = *(const float4*)&asr[c0 + 4];
    *(float4*)&adv[0] = *(const float4*)&ads[c0];
    *(float4*)&adv[4] = *(const float4*)&ads[c0 + 4];

    #pragma unroll
    for (int i = 0; i < 4; ++i) {
        int row = row0 + rg * 4 + i;
        float ps = 0.f, pd = 0.f;
        #pragma unroll
        for (int j = 0; j < 8; ++j) { ps += acc[i][j] * asv[j]; pd += acc[i][j] * adv[j]; }
        #pragma unroll
        for (int o = 1; o < 16; o <<= 1) { ps += __shfl_xor(ps, o); pd += __shfl_xor(pd, o); }
        if (row < N_NODES) {
            *(float4*)&H[(size_t)row * D + c0] =
                make_float4(acc[i][0], acc[i][1], acc[i][2], acc[i][3]);
            *(float4*)&H[(size_t)row * D + c0 + 4] =
                make_float4(acc[i][4], acc[i][5], acc[i][6], acc[i][7]);
            if (cg == 0) { als[row] = ps; ald[row] = pd; }
        }
    }
}

// ---------------- Edge softmax + aggregate: one wave per dst node ----------------
__global__ __launch_bounds__(256) void edge_kernel(
        const float* __restrict__ h, const float* __restrict__ als,
        const float* __restrict__ ald, const int* __restrict__ off,
        const int* __restrict__ csr, const float* __restrict__ bias,
        float* __restrict__ out) {
    int gtid = blockIdx.x * blockDim.x + threadIdx.x;
    int node = gtid >> 6;
    int lane = threadIdx.x & 63;
    if (node >= N_NODES) return;
    int beg = off[node], end = off[node + 1];
    int deg = end - beg;
    float ad = ald[node];

    // pass 1: segment max (lanes over edges)
    float lmax = -3.0e38f;
    for (int j = lane; j < deg; j += 64) {
        int s = csr[beg + j];
        float v = als[s] + ad;
        v = (v > 0.f) ? v : NEG_SLOPE * v;
        lmax = fmaxf(lmax, v);
    }
    #pragma unroll
    for (int o = 1; o < 64; o <<= 1) lmax = fmaxf(lmax, __shfl_xor(lmax, o));
    float m = lmax;

    // pass 2: denominator
    float lsum = 0.f;
    for (int j = lane; j < deg; j += 64) {
        int s = csr[beg + j];
        float v = als[s] + ad;
        v = (v > 0.f) ? v : NEG_SLOPE * v;
        lsum += __expf(v - m);
    }
    #pragma unroll
    for (int o = 1; o < 64; o <<= 1) lsum += __shfl_xor(lsum, o);
    float invden = 1.f / lsum;

    // pass 3: weighted aggregation (lanes over the 128 dims, serial over edges)
    float accx = 0.f, accy = 0.f;
    for (int e = 0; e < deg; ++e) {
        int s = csr[beg + e];              // broadcast load
        float v = als[s] + ad;
        v = (v > 0.f) ? v : NEG_SLOPE * v;
        float w = __expf(v - m) * invden;
        float2 hv = *(const float2*)(h + (size_t)s * D + lane * 2);
        accx += w * hv.x;
        accy += w * hv.y;
    }
    float2 bv = *(const float2*)(bias + lane * 2);
    *(float2*)(out + (size_t)node * D + lane * 2) = make_float2(accx + bv.x, accy + bv.y);
}

// ---------------- Pooling + readout ----------------
__global__ void bounds_kernel(const int* __restrict__ batch, int* __restrict__ gstart) {
    int g = blockIdx.x * blockDim.x + threadIdx.x;
    if (g > N_GRAPHS) return;
    if (g == N_GRAPHS) { gstart[g] = N_NODES; return; }
    int lo = 0, hi = N_NODES;
    while (lo < hi) { int mid = (lo + hi) >> 1; if (batch[mid] < g) lo = mid + 1; else hi = mid; }
    gstart[g] = lo;
}

__global__ void pool_kernel(const float* __restrict__ x, const int* __restrict__ gstart,
                            float* __restrict__ gpool) {
    int g = blockIdx.x >> 3, c = blockIdx.x & 7;
    int t = threadIdx.x;
    int beg = gstart[g], end = gstart[g + 1];
    float acc = 0.f;
    for (int i = beg + c; i < end; i += 8) acc += x[(size_t)i * D + t];
    atomicAdd(&gpool[g * D + t], acc);
}

__global__ void readout_kernel(const float* __restrict__ gpool,
                               const float* __restrict__ W1, const float* __restrict__ b1,
                               const float* __restrict__ W2, const float* __restrict__ b2,
                               float* __restrict__ out) {
    int g = blockIdx.x;
    int t = threadIdx.x;   // 64 threads
    __shared__ float hid[64];
    float a = b1[t];
    for (int k = 0; k < D; ++k) a += gpool[g * D + k] * W1[k * 64 + t];
    hid[t] = fmaxf(a, 0.f);
    __syncthreads();
    if (t < N_TARGETS) {
        float o = b2[t];
        for (int k = 0; k < 64; ++k) o += hid[k] * W2[k * N_TARGETS + t];
        out[g * N_TARGETS + t] = o;
    }
}

extern "C" void kernel_launch(void* const* d_in, const int* in_sizes, int n_in,
                              void* d_out, int out_size, void* d_ws, size_t ws_size,
                              hipStream_t stream) {
    const float* x    = (const float*)d_in[0];
    const int*   ei   = (const int*)d_in[1];
    const int*   batch= (const int*)d_in[2];
    const float* W    = (const float*)d_in[3];
    const float* a_s  = (const float*)d_in[4];
    const float* a_d  = (const float*)d_in[5];
    const float* bias = (const float*)d_in[6];
    const float* W1   = (const float*)d_in[7];
    const float* b1   = (const float*)d_in[8];
    const float* W2   = (const float*)d_in[9];
    const float* b2   = (const float*)d_in[10];
    float* out = (float*)d_out;
    const int* srcp = ei;
    const int* dstp = ei + N_EDGES;

    char* p = (char*)d_ws;
    float* bufA = (float*)p; p += (size_t)N_NODES * D * 4;
    float* bufB = (float*)p; p += (size_t)N_NODES * D * 4;
    float* h    = (float*)p; p += (size_t)N_NODES * D * 4;
    float* als  = (float*)p; p += (size_t)N_NODES * 4;
    float* ald  = (float*)p; p += (size_t)N_NODES * 4;
    int* deg    = (int*)p;   p += (size_t)N_NODES * 4;
    int* off    = (int*)p;   p += (size_t)(N_NODES + 1) * 4;
    int* cursor = (int*)p;   p += (size_t)N_NODES * 4;
    int* partials = (int*)p; p += 512 * 4;
    int* gstart = (int*)p;   p += 132 * 4;
    int* csr    = (int*)p;   p += (size_t)E_TOT * 4;
    float* gpool = (float*)p; p += N_GRAPHS * D * 4;

    hipMemsetAsync(deg, 0, N_NODES * 4, stream);
    hipMemsetAsync(cursor, 0, N_NODES * 4, stream);
    hipMemsetAsync(gpool, 0, N_GRAPHS * D * 4, stream);

    int eb = (E_TOT + 255) / 256;
    hist_kernel<<<eb, 256, 0, stream>>>(dstp, deg);
    scan1_kernel<<<NP, 256, 0, stream>>>(deg, off, partials);
    scan2_kernel<<<1, 512, 0, stream>>>(partials);
    scan3_kernel<<<NP, 256, 0, stream>>>(off, partials);
    scatter_kernel<<<eb, 256, 0, stream>>>(srcp, dstp, off, cursor, csr);
    bounds_kernel<<<1, 256, 0, stream>>>(batch, gstart);

    const float* cur = x;
    float* outs[3] = {bufA, bufB, bufA};
    for (int l = 0; l < N_LAYERS; ++l) {
        gemm_kernel<<<(N_NODES + 127) / 128, 512, 0, stream>>>(
            cur, W + (size_t)l * D * D, a_s + (size_t)l * D, a_d + (size_t)l * D,
            h, als, ald);
        edge_kernel<<<(N_NODES * 64 + 255) / 256, 256, 0, stream>>>(
            h, als, ald, off, csr, bias + (size_t)l * D, outs[l]);
        cur = outs[l];
    }
    pool_kernel<<<N_GRAPHS * 8, 128, 0, stream>>>(cur, gstart, gpool);
    readout_kernel<<<N_GRAPHS, 64, 0, stream>>>(gpool, W1, b1, W2, b2, out);
}

// Round 2
// 893.753 us; speedup vs baseline: 1.2790x; 1.2790x over previous
//
#include <hip/hip_runtime.h>
#include <math.h>

#define N_NODES 100000
#define N_EDGES 1600000
#define D 128
#define N_LAYERS 3
#define N_GRAPHS 128
#define N_TARGETS 10
#define NEG_SLOPE 0.2f
#define E_TOT (N_EDGES + N_NODES)
#define NP 391  /* ceil(N_NODES/256) */

// ---------------- CSR build ----------------
__global__ void hist_kernel(const int* __restrict__ dst, int* __restrict__ deg) {
    int i = blockIdx.x * blockDim.x + threadIdx.x;
    if (i >= E_TOT) return;
    int d = (i < N_EDGES) ? dst[i] : (i - N_EDGES);
    atomicAdd(&deg[d], 1);
}

__global__ void scan1_kernel(const int* __restrict__ deg, int* __restrict__ off,
                             int* __restrict__ partials) {
    __shared__ int s[256];
    int t = threadIdx.x;
    int i = blockIdx.x * 256 + t;
    int v = (i < N_NODES) ? deg[i] : 0;
    s[t] = v;
    __syncthreads();
    for (int o = 1; o < 256; o <<= 1) {
        int x = (t >= o) ? s[t - o] : 0;
        __syncthreads();
        s[t] += x;
        __syncthreads();
    }
    if (i < N_NODES) off[i + 1] = s[t];
    if (t == 255) partials[blockIdx.x] = s[255];
}

__global__ void scan2_kernel(int* __restrict__ partials) {
    __shared__ int s[512];
    int t = threadIdx.x;
    s[t] = (t < NP) ? partials[t] : 0;
    __syncthreads();
    for (int o = 1; o < 512; o <<= 1) {
        int x = (t >= o) ? s[t - o] : 0;
        __syncthreads();
        s[t] += x;
        __syncthreads();
    }
    if (t < NP) partials[t] = s[t];
}

__global__ void scan3_kernel(int* __restrict__ off, const int* __restrict__ partials) {
    int i = blockIdx.x * 256 + threadIdx.x;
    if (i == 0) off[0] = 0;
    if (i < N_NODES) {
        int b = i >> 8;
        if (b > 0) off[i + 1] += partials[b - 1];
    }
}

__global__ void scatter_kernel(const int* __restrict__ src, const int* __restrict__ dst,
                               const int* __restrict__ off, int* __restrict__ cursor,
                               int* __restrict__ csr_src) {
    int i = blockIdx.x * blockDim.x + threadIdx.x;
    if (i >= E_TOT) return;
    int s, d;
    if (i < N_EDGES) { s = src[i]; d = dst[i]; } else { s = d = i - N_EDGES; }
    int pos = off[d] + atomicAdd(&cursor[d], 1);
    csr_src[pos] = s;
}

// ---------------- GEMM: H = X @ W, als = H.a_src, ald = H.a_dst ----------------
__global__ __launch_bounds__(512) void gemm_kernel(
        const float* __restrict__ X, const float* __restrict__ Wl,
        const float* __restrict__ asr, const float* __restrict__ ads,
        float* __restrict__ H, float* __restrict__ als, float* __restrict__ ald) {
    __shared__ float xs[128][132];
    __shared__ float ws[128][128];
    int tid = threadIdx.x;
    int row0 = blockIdx.x * 128;

    for (int i = 0; i < 8; ++i) {
        int idx = (i * 512 + tid) * 4;
        int r = idx >> 7, c = idx & 127;
        *(float4*)&ws[r][c] = *(const float4*)&Wl[idx];
    }
    for (int i = 0; i < 8; ++i) {
        int idx = (i * 512 + tid) * 4;
        int r = idx >> 7, c = idx & 127;
        int row = row0 + r;
        float4 v = make_float4(0.f, 0.f, 0.f, 0.f);
        if (row < N_NODES) v = *(const float4*)&X[(size_t)row * D + c];
        *(float4*)&xs[r][c] = v;
    }
    __syncthreads();

    int cg = tid & 15;
    int rg = tid >> 4;
    int c0 = cg * 8;
    float acc[4][8];
    #pragma unroll
    for (int i = 0; i < 4; ++i)
        #pragma unroll
        for (int j = 0; j < 8; ++j) acc[i][j] = 0.f;

    #pragma unroll 4
    for (int k = 0; k < 128; ++k) {
        float4 wa = *(const float4*)&ws[k][c0];
        float4 wb = *(const float4*)&ws[k][c0 + 4];
        #pragma unroll
        for (int i = 0; i < 4; ++i) {
            float xv = xs[rg * 4 + i][k];
            acc[i][0] += xv * wa.x; acc[i][1] += xv * wa.y;
            acc[i][2] += xv * wa.z; acc[i][3] += xv * wa.w;
            acc[i][4] += xv * wb.x; acc[i][5] += xv * wb.y;
            acc[i][6] += xv * wb.z; acc[i][7] += xv * wb.w;
        }
    }

    float asv[8], adv[8];
    *(float4*)&asv[0] = *(const float4*)&asr[c0];
    *(float4*)&asv[4] = *(const float4*)&asr[c0 + 4];
    *(float4*)&adv[0] = *(const float4*)&ads[c0];
    *(float4*)&adv[4] = *(const float4*)&ads[c0 + 4];

    #pragma unroll
    for (int i = 0; i < 4; ++i) {
        int row = row0 + rg * 4 + i;
        float ps = 0.f, pd = 0.f;
        #pragma unroll
        for (int j = 0; j < 8; ++j) { ps += acc[i][j] * asv[j]; pd += acc[i][j] * adv[j]; }
        #pragma unroll
        for (int o = 1; o < 16; o <<= 1) { ps += __shfl_xor(ps, o); pd += __shfl_xor(pd, o); }
        if (row < N_NODES) {
            *(float4*)&H[(size_t)row * D + c0] =
                make_float4(acc[i][0], acc[i][1], acc[i][2], acc[i][3]);
            *(float4*)&H[(size_t)row * D + c0 + 4] =
                make_float4(acc[i][4], acc[i][5], acc[i][6], acc[i][7]);
            if (cg == 0) { als[row] = ps; ald[row] = pd; }
        }
    }
}

// ---------------- Edge softmax + aggregate: one wave per dst node ----------------
// Fast path (deg<=64): csr+als gathered ONCE into lane registers, softmax via
// register shuffles, aggregation loop broadcasts (s,w) via __shfl and issues 4
// independent 512B h-row gathers per iteration (ILP=4, zero per-edge scalar loads).
__global__ __launch_bounds__(256) void edge_kernel(
        const float* __restrict__ h, const float* __restrict__ als,
        const float* __restrict__ ald, const int* __restrict__ off,
        const int* __restrict__ csr, const float* __restrict__ bias,
        float* __restrict__ out) {
    int gtid = blockIdx.x * blockDim.x + threadIdx.x;
    int node = gtid >> 6;
    int lane = threadIdx.x & 63;
    if (node >= N_NODES) return;
    int beg = off[node], end = off[node + 1];
    int deg = end - beg;
    float ad = ald[node];
    float accx = 0.f, accy = 0.f;
    const float* hl = h + lane * 2;

    if (deg <= 64) {
        int sreg = 0;
        float v = -3.0e38f;
        if (lane < deg) {
            sreg = csr[beg + lane];
            float t = als[sreg] + ad;
            v = (t > 0.f) ? t : NEG_SLOPE * t;
        }
        float m = v;
        #pragma unroll
        for (int o = 1; o < 64; o <<= 1) m = fmaxf(m, __shfl_xor(m, o));
        float w = (lane < deg) ? __expf(v - m) : 0.f;
        float sum = w;
        #pragma unroll
        for (int o = 1; o < 64; o <<= 1) sum += __shfl_xor(sum, o);
        w *= 1.f / sum;

        int e = 0;
        for (; e + 4 <= deg; e += 4) {
            int s0 = __shfl(sreg, e + 0), s1 = __shfl(sreg, e + 1),
                s2 = __shfl(sreg, e + 2), s3 = __shfl(sreg, e + 3);
            float w0 = __shfl(w, e + 0), w1 = __shfl(w, e + 1),
                  w2 = __shfl(w, e + 2), w3 = __shfl(w, e + 3);
            float2 h0 = *(const float2*)(hl + (size_t)s0 * D);
            float2 h1 = *(const float2*)(hl + (size_t)s1 * D);
            float2 h2 = *(const float2*)(hl + (size_t)s2 * D);
            float2 h3 = *(const float2*)(hl + (size_t)s3 * D);
            accx += w0 * h0.x; accy += w0 * h0.y;
            accx += w1 * h1.x; accy += w1 * h1.y;
            accx += w2 * h2.x; accy += w2 * h2.y;
            accx += w3 * h3.x; accy += w3 * h3.y;
        }
        for (; e < deg; ++e) {
            int s0 = __shfl(sreg, e);
            float w0 = __shfl(w, e);
            float2 h0 = *(const float2*)(hl + (size_t)s0 * D);
            accx += w0 * h0.x; accy += w0 * h0.y;
        }
    } else {
        // generic fallback (any degree)
        float lmax = -3.0e38f;
        for (int j = lane; j < deg; j += 64) {
            int s = csr[beg + j];
            float t = als[s] + ad;
            t = (t > 0.f) ? t : NEG_SLOPE * t;
            lmax = fmaxf(lmax, t);
        }
        #pragma unroll
        for (int o = 1; o < 64; o <<= 1) lmax = fmaxf(lmax, __shfl_xor(lmax, o));
        float m = lmax;
        float lsum = 0.f;
        for (int j = lane; j < deg; j += 64) {
            int s = csr[beg + j];
            float t = als[s] + ad;
            t = (t > 0.f) ? t : NEG_SLOPE * t;
            lsum += __expf(t - m);
        }
        #pragma unroll
        for (int o = 1; o < 64; o <<= 1) lsum += __shfl_xor(lsum, o);
        float invden = 1.f / lsum;
        for (int e = 0; e < deg; ++e) {
            int s = csr[beg + e];
            float t = als[s] + ad;
            t = (t > 0.f) ? t : NEG_SLOPE * t;
            float w = __expf(t - m) * invden;
            float2 hv = *(const float2*)(hl + (size_t)s * D);
            accx += w * hv.x; accy += w * hv.y;
        }
    }

    float2 bv = *(const float2*)(bias + lane * 2);
    *(float2*)(out + (size_t)node * D + lane * 2) = make_float2(accx + bv.x, accy + bv.y);
}

// ---------------- Pooling + readout ----------------
__global__ void bounds_kernel(const int* __restrict__ batch, int* __restrict__ gstart) {
    int g = blockIdx.x * blockDim.x + threadIdx.x;
    if (g > N_GRAPHS) return;
    if (g == N_GRAPHS) { gstart[g] = N_NODES; return; }
    int lo = 0, hi = N_NODES;
    while (lo < hi) { int mid = (lo + hi) >> 1; if (batch[mid] < g) lo = mid + 1; else hi = mid; }
    gstart[g] = lo;
}

__global__ void pool_kernel(const float* __restrict__ x, const int* __restrict__ gstart,
                            float* __restrict__ gpool) {
    int g = blockIdx.x >> 3, c = blockIdx.x & 7;
    int t = threadIdx.x;
    int beg = gstart[g], end = gstart[g + 1];
    float acc = 0.f;
    for (int i = beg + c; i < end; i += 8) acc += x[(size_t)i * D + t];
    atomicAdd(&gpool[g * D + t], acc);
}

__global__ void readout_kernel(const float* __restrict__ gpool,
                               const float* __restrict__ W1, const float* __restrict__ b1,
                               const float* __restrict__ W2, const float* __restrict__ b2,
                               float* __restrict__ out) {
    int g = blockIdx.x;
    int t = threadIdx.x;   // 64 threads
    __shared__ float hid[64];
    float a = b1[t];
    for (int k = 0; k < D; ++k) a += gpool[g * D + k] * W1[k * 64 + t];
    hid[t] = fmaxf(a, 0.f);
    __syncthreads();
    if (t < N_TARGETS) {
        float o = b2[t];
        for (int k = 0; k < 64; ++k) o += hid[k] * W2[k * N_TARGETS + t];
        out[g * N_TARGETS + t] = o;
    }
}

extern "C" void kernel_launch(void* const* d_in, const int* in_sizes, int n_in,
                              void* d_out, int out_size, void* d_ws, size_t ws_size,
                              hipStream_t stream) {
    const float* x    = (const float*)d_in[0];
    const int*   ei   = (const int*)d_in[1];
    const int*   batch= (const int*)d_in[2];
    const float* W    = (const float*)d_in[3];
    const float* a_s  = (const float*)d_in[4];
    const float* a_d  = (const float*)d_in[5];
    const float* bias = (const float*)d_in[6];
    const float* W1   = (const float*)d_in[7];
    const float* b1   = (const float*)d_in[8];
    const float* W2   = (const float*)d_in[9];
    const float* b2   = (const float*)d_in[10];
    float* out = (float*)d_out;
    const int* srcp = ei;
    const int* dstp = ei + N_EDGES;

    char* p = (char*)d_ws;
    float* bufA = (float*)p; p += (size_t)N_NODES * D * 4;
    float* bufB = (float*)p; p += (size_t)N_NODES * D * 4;
    float* h    = (float*)p; p += (size_t)N_NODES * D * 4;
    float* als  = (float*)p; p += (size_t)N_NODES * 4;
    float* ald  = (float*)p; p += (size_t)N_NODES * 4;
    int* deg    = (int*)p;   p += (size_t)N_NODES * 4;
    int* off    = (int*)p;   p += (size_t)(N_NODES + 1) * 4;
    int* cursor = (int*)p;   p += (size_t)N_NODES * 4;
    int* partials = (int*)p; p += 512 * 4;
    int* gstart = (int*)p;   p += 132 * 4;
    int* csr    = (int*)p;   p += (size_t)E_TOT * 4;
    float* gpool = (float*)p; p += N_GRAPHS * D * 4;

    hipMemsetAsync(deg, 0, N_NODES * 4, stream);
    hipMemsetAsync(cursor, 0, N_NODES * 4, stream);
    hipMemsetAsync(gpool, 0, N_GRAPHS * D * 4, stream);

    int eb = (E_TOT + 255) / 256;
    hist_kernel<<<eb, 256, 0, stream>>>(dstp, deg);
    scan1_kernel<<<NP, 256, 0, stream>>>(deg, off, partials);
    scan2_kernel<<<1, 512, 0, stream>>>(partials);
    scan3_kernel<<<NP, 256, 0, stream>>>(off, partials);
    scatter_kernel<<<eb, 256, 0, stream>>>(srcp, dstp, off, cursor, csr);
    bounds_kernel<<<1, 256, 0, stream>>>(batch, gstart);

    const float* cur = x;
    float* outs[3] = {bufA, bufB, bufA};
    for (int l = 0; l < N_LAYERS; ++l) {
        gemm_kernel<<<(N_NODES + 127) / 128, 512, 0, stream>>>(
            cur, W + (size_t)l * D * D, a_s + (size_t)l * D, a_d + (size_t)l * D,
            h, als, ald);
        edge_kernel<<<(N_NODES * 64 + 255) / 256, 256, 0, stream>>>(
            h, als, ald, off, csr, bias + (size_t)l * D, outs[l]);
        cur = outs[l];
    }
    pool_kernel<<<N_GRAPHS * 8, 128, 0, stream>>>(cur, gstart, gpool);
    readout_kernel<<<N_GRAPHS, 64, 0, stream>>>(gpool, W1, b1, W2, b2, out);
}

// Round 3
// 754.350 us; speedup vs baseline: 1.5154x; 1.1848x over previous
//
#include <hip/hip_runtime.h>
#include <math.h>

#define N_NODES 100000
#define N_EDGES 1600000
#define D 128
#define N_LAYERS 3
#define N_GRAPHS 128
#define N_TARGETS 10
#define NEG_SLOPE 0.2f
#define E_TOT (N_EDGES + N_NODES)
#define NP 391  /* ceil(N_NODES/256) */

typedef unsigned int u32;
typedef unsigned short u16;

__device__ __forceinline__ float bf2f(u16 b) {
    u32 u = ((u32)b) << 16;
    return __uint_as_float(u);
}
__device__ __forceinline__ u16 f2bf(float f) {  // round-to-nearest-even
    u32 u = __float_as_uint(f);
    u32 r = (u + 0x7fffu + ((u >> 16) & 1u)) >> 16;
    return (u16)r;
}

// ---------------- CSR build ----------------
__global__ void hist_kernel(const int* __restrict__ dst, int* __restrict__ deg) {
    int i = blockIdx.x * blockDim.x + threadIdx.x;
    if (i >= E_TOT) return;
    int d = (i < N_EDGES) ? dst[i] : (i - N_EDGES);
    atomicAdd(&deg[d], 1);
}

__global__ void scan1_kernel(const int* __restrict__ deg, int* __restrict__ off,
                             int* __restrict__ partials) {
    __shared__ int s[256];
    int t = threadIdx.x;
    int i = blockIdx.x * 256 + t;
    int v = (i < N_NODES) ? deg[i] : 0;
    s[t] = v;
    __syncthreads();
    for (int o = 1; o < 256; o <<= 1) {
        int x = (t >= o) ? s[t - o] : 0;
        __syncthreads();
        s[t] += x;
        __syncthreads();
    }
    if (i < N_NODES) off[i + 1] = s[t];
    if (t == 255) partials[blockIdx.x] = s[255];
}

__global__ void scan2_kernel(int* __restrict__ partials) {
    __shared__ int s[512];
    int t = threadIdx.x;
    s[t] = (t < NP) ? partials[t] : 0;
    __syncthreads();
    for (int o = 1; o < 512; o <<= 1) {
        int x = (t >= o) ? s[t - o] : 0;
        __syncthreads();
        s[t] += x;
        __syncthreads();
    }
    if (t < NP) partials[t] = s[t];
}

__global__ void scan3_kernel(int* __restrict__ off, const int* __restrict__ partials) {
    int i = blockIdx.x * 256 + threadIdx.x;
    if (i == 0) off[0] = 0;
    if (i < N_NODES) {
        int b = i >> 8;
        if (b > 0) off[i + 1] += partials[b - 1];
    }
}

__global__ void scatter_kernel(const int* __restrict__ src, const int* __restrict__ dst,
                               const int* __restrict__ off, int* __restrict__ cursor,
                               int* __restrict__ csr_src) {
    int i = blockIdx.x * blockDim.x + threadIdx.x;
    if (i >= E_TOT) return;
    int s, d;
    if (i < N_EDGES) { s = src[i]; d = dst[i]; } else { s = d = i - N_EDGES; }
    int pos = off[d] + atomicAdd(&cursor[d], 1);
    csr_src[pos] = s;
}

// ---------------- GEMM: Hb(bf16) = X @ W, als = H.a_src, ald = H.a_dst ----------------
__global__ __launch_bounds__(512) void gemm_kernel(
        const float* __restrict__ X, const float* __restrict__ Wl,
        const float* __restrict__ asr, const float* __restrict__ ads,
        u16* __restrict__ Hb, float* __restrict__ als, float* __restrict__ ald) {
    __shared__ float xs[128][132];
    __shared__ float ws[128][128];
    int tid = threadIdx.x;
    int row0 = blockIdx.x * 128;

    for (int i = 0; i < 8; ++i) {
        int idx = (i * 512 + tid) * 4;
        int r = idx >> 7, c = idx & 127;
        *(float4*)&ws[r][c] = *(const float4*)&Wl[idx];
    }
    for (int i = 0; i < 8; ++i) {
        int idx = (i * 512 + tid) * 4;
        int r = idx >> 7, c = idx & 127;
        int row = row0 + r;
        float4 v = make_float4(0.f, 0.f, 0.f, 0.f);
        if (row < N_NODES) v = *(const float4*)&X[(size_t)row * D + c];
        *(float4*)&xs[r][c] = v;
    }
    __syncthreads();

    int cg = tid & 15;
    int rg = tid >> 4;
    int c0 = cg * 8;
    float acc[4][8];
    #pragma unroll
    for (int i = 0; i < 4; ++i)
        #pragma unroll
        for (int j = 0; j < 8; ++j) acc[i][j] = 0.f;

    #pragma unroll 4
    for (int k = 0; k < 128; ++k) {
        float4 wa = *(const float4*)&ws[k][c0];
        float4 wb = *(const float4*)&ws[k][c0 + 4];
        #pragma unroll
        for (int i = 0; i < 4; ++i) {
            float xv = xs[rg * 4 + i][k];
            acc[i][0] += xv * wa.x; acc[i][1] += xv * wa.y;
            acc[i][2] += xv * wa.z; acc[i][3] += xv * wa.w;
            acc[i][4] += xv * wb.x; acc[i][5] += xv * wb.y;
            acc[i][6] += xv * wb.z; acc[i][7] += xv * wb.w;
        }
    }

    float asv[8], adv[8];
    *(float4*)&asv[0] = *(const float4*)&asr[c0];
    *(float4*)&asv[4] = *(const float4*)&asr[c0 + 4];
    *(float4*)&adv[0] = *(const float4*)&ads[c0];
    *(float4*)&adv[4] = *(const float4*)&ads[c0 + 4];

    #pragma unroll
    for (int i = 0; i < 4; ++i) {
        int row = row0 + rg * 4 + i;
        float ps = 0.f, pd = 0.f;
        #pragma unroll
        for (int j = 0; j < 8; ++j) { ps += acc[i][j] * asv[j]; pd += acc[i][j] * adv[j]; }
        #pragma unroll
        for (int o = 1; o < 16; o <<= 1) { ps += __shfl_xor(ps, o); pd += __shfl_xor(pd, o); }
        if (row < N_NODES) {
            u32 p0 = (u32)f2bf(acc[i][0]) | ((u32)f2bf(acc[i][1]) << 16);
            u32 p1 = (u32)f2bf(acc[i][2]) | ((u32)f2bf(acc[i][3]) << 16);
            u32 p2 = (u32)f2bf(acc[i][4]) | ((u32)f2bf(acc[i][5]) << 16);
            u32 p3 = (u32)f2bf(acc[i][6]) | ((u32)f2bf(acc[i][7]) << 16);
            uint4 pk = make_uint4(p0, p1, p2, p3);
            *(uint4*)&Hb[(size_t)row * D + c0] = pk;
            if (cg == 0) { als[row] = ps; ald[row] = pd; }
        }
    }
}

// ---------------- Edge softmax + aggregate: one wave per dst node ----------------
// Fast path (deg<=64): csr+als gathered ONCE into lane registers, softmax via
// register shuffles; aggregation broadcasts (s,w) via __shfl and issues 8
// independent 256B bf16 h-row gathers per iteration (ILP=8).
__global__ __launch_bounds__(256) void edge_kernel(
        const u16* __restrict__ hb, const float* __restrict__ als,
        const float* __restrict__ ald, const int* __restrict__ off,
        const int* __restrict__ csr, const float* __restrict__ bias,
        float* __restrict__ out) {
    int gtid = blockIdx.x * blockDim.x + threadIdx.x;
    int node = gtid >> 6;
    int lane = threadIdx.x & 63;
    if (node >= N_NODES) return;
    int beg = off[node], end = off[node + 1];
    int deg = end - beg;
    float ad = ald[node];
    float accx = 0.f, accy = 0.f;
    const u16* hl = hb + lane * 2;

    if (deg <= 64) {
        int sreg = 0;
        float v = -3.0e38f;
        if (lane < deg) {
            sreg = csr[beg + lane];
            float t = als[sreg] + ad;
            v = (t > 0.f) ? t : NEG_SLOPE * t;
        }
        float m = v;
        #pragma unroll
        for (int o = 1; o < 64; o <<= 1) m = fmaxf(m, __shfl_xor(m, o));
        float w = (lane < deg) ? __expf(v - m) : 0.f;
        float sum = w;
        #pragma unroll
        for (int o = 1; o < 64; o <<= 1) sum += __shfl_xor(sum, o);
        w *= 1.f / sum;

        int e = 0;
        for (; e + 8 <= deg; e += 8) {
            int s[8]; float wv[8]; ushort2 hv[8];
            #pragma unroll
            for (int k = 0; k < 8; ++k) { s[k] = __shfl(sreg, e + k); wv[k] = __shfl(w, e + k); }
            #pragma unroll
            for (int k = 0; k < 8; ++k) hv[k] = *(const ushort2*)(hl + (size_t)s[k] * D);
            #pragma unroll
            for (int k = 0; k < 8; ++k) {
                accx += wv[k] * bf2f(hv[k].x);
                accy += wv[k] * bf2f(hv[k].y);
            }
        }
        for (; e < deg; ++e) {
            int s0 = __shfl(sreg, e);
            float w0 = __shfl(w, e);
            ushort2 h0 = *(const ushort2*)(hl + (size_t)s0 * D);
            accx += w0 * bf2f(h0.x);
            accy += w0 * bf2f(h0.y);
        }
    } else {
        // generic fallback (any degree)
        float lmax = -3.0e38f;
        for (int j = lane; j < deg; j += 64) {
            int s = csr[beg + j];
            float t = als[s] + ad;
            t = (t > 0.f) ? t : NEG_SLOPE * t;
            lmax = fmaxf(lmax, t);
        }
        #pragma unroll
        for (int o = 1; o < 64; o <<= 1) lmax = fmaxf(lmax, __shfl_xor(lmax, o));
        float m = lmax;
        float lsum = 0.f;
        for (int j = lane; j < deg; j += 64) {
            int s = csr[beg + j];
            float t = als[s] + ad;
            t = (t > 0.f) ? t : NEG_SLOPE * t;
            lsum += __expf(t - m);
        }
        #pragma unroll
        for (int o = 1; o < 64; o <<= 1) lsum += __shfl_xor(lsum, o);
        float invden = 1.f / lsum;
        for (int e = 0; e < deg; ++e) {
            int s = csr[beg + e];
            float t = als[s] + ad;
            t = (t > 0.f) ? t : NEG_SLOPE * t;
            float w = __expf(t - m) * invden;
            ushort2 hv = *(const ushort2*)(hl + (size_t)s * D);
            accx += w * bf2f(hv.x);
            accy += w * bf2f(hv.y);
        }
    }

    float2 bv = *(const float2*)(bias + lane * 2);
    *(float2*)(out + (size_t)node * D + lane * 2) = make_float2(accx + bv.x, accy + bv.y);
}

// ---------------- Pooling + readout ----------------
__global__ void bounds_kernel(const int* __restrict__ batch, int* __restrict__ gstart) {
    int g = blockIdx.x * blockDim.x + threadIdx.x;
    if (g > N_GRAPHS) return;
    if (g == N_GRAPHS) { gstart[g] = N_NODES; return; }
    int lo = 0, hi = N_NODES;
    while (lo < hi) { int mid = (lo + hi) >> 1; if (batch[mid] < g) lo = mid + 1; else hi = mid; }
    gstart[g] = lo;
}

__global__ void pool_kernel(const float* __restrict__ x, const int* __restrict__ gstart,
                            float* __restrict__ gpool) {
    int g = blockIdx.x >> 3, c = blockIdx.x & 7;
    int t = threadIdx.x;
    int beg = gstart[g], end = gstart[g + 1];
    float acc = 0.f;
    for (int i = beg + c; i < end; i += 8) acc += x[(size_t)i * D + t];
    atomicAdd(&gpool[g * D + t], acc);
}

__global__ void readout_kernel(const float* __restrict__ gpool,
                               const float* __restrict__ W1, const float* __restrict__ b1,
                               const float* __restrict__ W2, const float* __restrict__ b2,
                               float* __restrict__ out) {
    int g = blockIdx.x;
    int t = threadIdx.x;   // 64 threads
    __shared__ float hid[64];
    float a = b1[t];
    for (int k = 0; k < D; ++k) a += gpool[g * D + k] * W1[k * 64 + t];
    hid[t] = fmaxf(a, 0.f);
    __syncthreads();
    if (t < N_TARGETS) {
        float o = b2[t];
        for (int k = 0; k < 64; ++k) o += hid[k] * W2[k * N_TARGETS + t];
        out[g * N_TARGETS + t] = o;
    }
}

extern "C" void kernel_launch(void* const* d_in, const int* in_sizes, int n_in,
                              void* d_out, int out_size, void* d_ws, size_t ws_size,
                              hipStream_t stream) {
    const float* x    = (const float*)d_in[0];
    const int*   ei   = (const int*)d_in[1];
    const int*   batch= (const int*)d_in[2];
    const float* W    = (const float*)d_in[3];
    const float* a_s  = (const float*)d_in[4];
    const float* a_d  = (const float*)d_in[5];
    const float* bias = (const float*)d_in[6];
    const float* W1   = (const float*)d_in[7];
    const float* b1   = (const float*)d_in[8];
    const float* W2   = (const float*)d_in[9];
    const float* b2   = (const float*)d_in[10];
    float* out = (float*)d_out;
    const int* srcp = ei;
    const int* dstp = ei + N_EDGES;

    char* p = (char*)d_ws;
    float* bufA = (float*)p; p += (size_t)N_NODES * D * 4;
    float* bufB = (float*)p; p += (size_t)N_NODES * D * 4;
    u16* hb     = (u16*)p;   p += (size_t)N_NODES * D * 2;
    float* als  = (float*)p; p += (size_t)N_NODES * 4;
    float* ald  = (float*)p; p += (size_t)N_NODES * 4;
    int* deg    = (int*)p;   p += (size_t)N_NODES * 4;
    int* off    = (int*)p;   p += (size_t)(N_NODES + 1) * 4;
    int* cursor = (int*)p;   p += (size_t)N_NODES * 4;
    int* partials = (int*)p; p += 512 * 4;
    int* gstart = (int*)p;   p += 132 * 4;
    int* csr    = (int*)p;   p += (size_t)E_TOT * 4;
    float* gpool = (float*)p; p += N_GRAPHS * D * 4;

    hipMemsetAsync(deg, 0, N_NODES * 4, stream);
    hipMemsetAsync(cursor, 0, N_NODES * 4, stream);
    hipMemsetAsync(gpool, 0, N_GRAPHS * D * 4, stream);

    int eb = (E_TOT + 255) / 256;
    hist_kernel<<<eb, 256, 0, stream>>>(dstp, deg);
    scan1_kernel<<<NP, 256, 0, stream>>>(deg, off, partials);
    scan2_kernel<<<1, 512, 0, stream>>>(partials);
    scan3_kernel<<<NP, 256, 0, stream>>>(off, partials);
    scatter_kernel<<<eb, 256, 0, stream>>>(srcp, dstp, off, cursor, csr);
    bounds_kernel<<<1, 256, 0, stream>>>(batch, gstart);

    const float* cur = x;
    float* outs[3] = {bufA, bufB, bufA};
    for (int l = 0; l < N_LAYERS; ++l) {
        gemm_kernel<<<(N_NODES + 127) / 128, 512, 0, stream>>>(
            cur, W + (size_t)l * D * D, a_s + (size_t)l * D, a_d + (size_t)l * D,
            hb, als, ald);
        edge_kernel<<<(N_NODES * 64 + 255) / 256, 256, 0, stream>>>(
            hb, als, ald, off, csr, bias + (size_t)l * D, outs[l]);
        cur = outs[l];
    }
    pool_kernel<<<N_GRAPHS * 8, 128, 0, stream>>>(cur, gstart, gpool);
    readout_kernel<<<N_GRAPHS, 64, 0, stream>>>(gpool, W1, b1, W2, b2, out);
}

// Round 5
// 711.069 us; speedup vs baseline: 1.6076x; 1.0609x over previous
//
#include <hip/hip_runtime.h>
#include <math.h>

#define N_NODES 100000
#define N_EDGES 1600000
#define D 128
#define N_LAYERS 3
#define N_GRAPHS 128
#define N_TARGETS 10
#define NEG_SLOPE 0.2f
#define E_TOT (N_EDGES + N_NODES)
#define CSR_W 64   /* fixed-width CSR rows; deg>64 handled by fallback scan */

typedef unsigned int u32;
typedef unsigned short u16;

__device__ __forceinline__ float bf2f(u16 b) {
    u32 u = ((u32)b) << 16;
    return __uint_as_float(u);
}
__device__ __forceinline__ u16 f2bf(float f) {  // round-to-nearest-even
    u32 u = __float_as_uint(f);
    u32 r = (u + 0x7fffu + ((u >> 16) & 1u)) >> 16;
    return (u16)r;
}

// ---------------- CSR build: ONE kernel, fixed-width rows ----------------
__global__ void build_kernel(const int* __restrict__ src, const int* __restrict__ dst,
                             int* __restrict__ deg, int* __restrict__ csrf) {
    int i = blockIdx.x * blockDim.x + threadIdx.x;
    if (i >= E_TOT) return;
    int s, d;
    if (i < N_EDGES) { s = src[i]; d = dst[i]; } else { s = d = i - N_EDGES; }
    int r = atomicAdd(&deg[d], 1);
    if (r < CSR_W) csrf[d * CSR_W + r] = s;
}

// ---------------- GEMM: Hb(bf16) = X @ W, als = H.a_src, ald = H.a_dst ----------------
__global__ __launch_bounds__(512) void gemm_kernel(
        const float* __restrict__ X, const float* __restrict__ Wl,
        const float* __restrict__ asr, const float* __restrict__ ads,
        u16* __restrict__ Hb, float* __restrict__ als, float* __restrict__ ald) {
    __shared__ float xs[128][132];
    __shared__ float ws[128][128];
    int tid = threadIdx.x;
    int row0 = blockIdx.x * 128;

    for (int i = 0; i < 8; ++i) {
        int idx = (i * 512 + tid) * 4;
        int r = idx >> 7, c = idx & 127;
        *(float4*)&ws[r][c] = *(const float4*)&Wl[idx];
    }
    for (int i = 0; i < 8; ++i) {
        int idx = (i * 512 + tid) * 4;
        int r = idx >> 7, c = idx & 127;
        int row = row0 + r;
        float4 v = make_float4(0.f, 0.f, 0.f, 0.f);
        if (row < N_NODES) v = *(const float4*)&X[(size_t)row * D + c];
        *(float4*)&xs[r][c] = v;
    }
    __syncthreads();

    int cg = tid & 15;
    int rg = tid >> 4;
    int c0 = cg * 8;
    float acc[4][8];
    #pragma unroll
    for (int i = 0; i < 4; ++i)
        #pragma unroll
        for (int j = 0; j < 8; ++j) acc[i][j] = 0.f;

    #pragma unroll 4
    for (int k = 0; k < 128; ++k) {
        float4 wa = *(const float4*)&ws[k][c0];
        float4 wb = *(const float4*)&ws[k][c0 + 4];
        #pragma unroll
        for (int i = 0; i < 4; ++i) {
            float xv = xs[rg * 4 + i][k];
            acc[i][0] += xv * wa.x; acc[i][1] += xv * wa.y;
            acc[i][2] += xv * wa.z; acc[i][3] += xv * wa.w;
            acc[i][4] += xv * wb.x; acc[i][5] += xv * wb.y;
            acc[i][6] += xv * wb.z; acc[i][7] += xv * wb.w;
        }
    }

    float asv[8], adv[8];
    *(float4*)&asv[0] = *(const float4*)&asr[c0];
    *(float4*)&asv[4] = *(const float4*)&asr[c0 + 4];
    *(float4*)&adv[0] = *(const float4*)&ads[c0];
    *(float4*)&adv[4] = *(const float4*)&ads[c0 + 4];

    #pragma unroll
    for (int i = 0; i < 4; ++i) {
        int row = row0 + rg * 4 + i;
        float ps = 0.f, pd = 0.f;
        #pragma unroll
        for (int j = 0; j < 8; ++j) { ps += acc[i][j] * asv[j]; pd += acc[i][j] * adv[j]; }
        #pragma unroll
        for (int o = 1; o < 16; o <<= 1) { ps += __shfl_xor(ps, o); pd += __shfl_xor(pd, o); }
        if (row < N_NODES) {
            u32 p0 = (u32)f2bf(acc[i][0]) | ((u32)f2bf(acc[i][1]) << 16);
            u32 p1 = (u32)f2bf(acc[i][2]) | ((u32)f2bf(acc[i][3]) << 16);
            u32 p2 = (u32)f2bf(acc[i][4]) | ((u32)f2bf(acc[i][5]) << 16);
            u32 p3 = (u32)f2bf(acc[i][6]) | ((u32)f2bf(acc[i][7]) << 16);
            uint4 pk = make_uint4(p0, p1, p2, p3);
            *(uint4*)&Hb[(size_t)row * D + c0] = pk;
            if (cg == 0) { als[row] = ps; ald[row] = pd; }
        }
    }
}

// ---------------- Edge softmax + aggregate: one wave per dst node ----------------
__global__ __launch_bounds__(256) void edge_kernel(
        const u16* __restrict__ hb, const float* __restrict__ als,
        const float* __restrict__ ald, const int* __restrict__ deg_arr,
        const int* __restrict__ csrf, const float* __restrict__ bias,
        const int* __restrict__ esrc, const int* __restrict__ edst,
        float* __restrict__ out) {
    int gtid = blockIdx.x * blockDim.x + threadIdx.x;
    int node = gtid >> 6;
    int lane = threadIdx.x & 63;
    if (node >= N_NODES) return;
    int deg = deg_arr[node];
    float ad = ald[node];
    float accx = 0.f, accy = 0.f;
    const u16* hl = hb + lane * 2;

    if (deg <= CSR_W) {
        // fast path: coalesced fixed-width row, softmax fully in registers
        int sreg = 0;
        float v = -3.0e38f;
        if (lane < deg) {
            sreg = csrf[node * CSR_W + lane];
            float t = als[sreg] + ad;
            v = (t > 0.f) ? t : NEG_SLOPE * t;
        }
        float m = v;
        #pragma unroll
        for (int o = 1; o < 64; o <<= 1) m = fmaxf(m, __shfl_xor(m, o));
        float w = (lane < deg) ? __expf(v - m) : 0.f;
        float sum = w;
        #pragma unroll
        for (int o = 1; o < 64; o <<= 1) sum += __shfl_xor(sum, o);
        w *= 1.f / sum;

        int e = 0;
        for (; e + 8 <= deg; e += 8) {
            int s[8]; float wv[8]; ushort2 hv[8];
            #pragma unroll
            for (int k = 0; k < 8; ++k) { s[k] = __shfl(sreg, e + k); wv[k] = __shfl(w, e + k); }
            #pragma unroll
            for (int k = 0; k < 8; ++k) hv[k] = *(const ushort2*)(hl + (size_t)s[k] * D);
            #pragma unroll
            for (int k = 0; k < 8; ++k) {
                accx += wv[k] * bf2f(hv[k].x);
                accy += wv[k] * bf2f(hv[k].y);
            }
        }
        for (; e < deg; ++e) {
            int s0 = __shfl(sreg, e);
            float w0 = __shfl(w, e);
            ushort2 h0 = *(const ushort2*)(hl + (size_t)s0 * D);
            accx += w0 * bf2f(h0.x);
            accy += w0 * bf2f(h0.y);
        }
    } else {
        // overflow fallback (deg > CSR_W): scan the raw edge list. Correct for any
        // degree; statistically never taken at Poisson(17) degrees.
        float lm = -3.0e38f;
        for (int j = lane; j < E_TOT; j += 64) {
            int d = (j < N_EDGES) ? edst[j] : (j - N_EDGES);
            if (d == node) {
                int s = (j < N_EDGES) ? esrc[j] : (j - N_EDGES);
                float t = als[s] + ad;
                t = (t > 0.f) ? t : NEG_SLOPE * t;
                lm = fmaxf(lm, t);
            }
        }
        #pragma unroll
        for (int o = 1; o < 64; o <<= 1) lm = fmaxf(lm, __shfl_xor(lm, o));
        float m = lm;
        float lsum = 0.f;
        for (int j = lane; j < E_TOT; j += 64) {
            int d = (j < N_EDGES) ? edst[j] : (j - N_EDGES);
            if (d == node) {
                int s = (j < N_EDGES) ? esrc[j] : (j - N_EDGES);
                float t = als[s] + ad;
                t = (t > 0.f) ? t : NEG_SLOPE * t;
                lsum += __expf(t - m);
            }
        }
        #pragma unroll
        for (int o = 1; o < 64; o <<= 1) lsum += __shfl_xor(lsum, o);
        float invden = 1.f / lsum;
        for (int base = 0; base < E_TOT; base += 64) {
            int j = base + lane;
            int d = -1;
            if (j < E_TOT) d = (j < N_EDGES) ? edst[j] : (j - N_EDGES);
            unsigned long long mask = __ballot(d == node);
            while (mask) {
                int b = __ffsll(mask) - 1;
                mask &= mask - 1;
                int jj = base + b;
                int s = (jj < N_EDGES) ? esrc[jj] : (jj - N_EDGES);
                float t = als[s] + ad;
                t = (t > 0.f) ? t : NEG_SLOPE * t;
                float w = __expf(t - m) * invden;
                ushort2 hv = *(const ushort2*)(hl + (size_t)s * D);
                accx += w * bf2f(hv.x);
                accy += w * bf2f(hv.y);
            }
        }
    }

    float2 bv = *(const float2*)(bias + lane * 2);
    *(float2*)(out + (size_t)node * D + lane * 2) = make_float2(accx + bv.x, accy + bv.y);
}

// ---------------- Pooling + readout ----------------
__global__ void bounds_kernel(const int* __restrict__ batch, int* __restrict__ gstart) {
    int g = blockIdx.x * blockDim.x + threadIdx.x;
    if (g > N_GRAPHS) return;
    if (g == N_GRAPHS) { gstart[g] = N_NODES; return; }
    int lo = 0, hi = N_NODES;
    while (lo < hi) { int mid = (lo + hi) >> 1; if (batch[mid] < g) lo = mid + 1; else hi = mid; }
    gstart[g] = lo;
}

__global__ void pool_kernel(const float* __restrict__ x, const int* __restrict__ gstart,
                            float* __restrict__ gpool) {
    int g = blockIdx.x >> 3, c = blockIdx.x & 7;
    int t = threadIdx.x;
    int beg = gstart[g], end = gstart[g + 1];
    float acc = 0.f;
    for (int i = beg + c; i < end; i += 8) acc += x[(size_t)i * D + t];
    atomicAdd(&gpool[g * D + t], acc);
}

__global__ void readout_kernel(const float* __restrict__ gpool,
                               const float* __restrict__ W1, const float* __restrict__ b1,
                               const float* __restrict__ W2, const float* __restrict__ b2,
                               float* __restrict__ out) {
    int g = blockIdx.x;
    int t = threadIdx.x;   // 64 threads
    __shared__ float hid[64];
    float a = b1[t];
    for (int k = 0; k < D; ++k) a += gpool[g * D + k] * W1[k * 64 + t];
    hid[t] = fmaxf(a, 0.f);
    __syncthreads();
    if (t < N_TARGETS) {
        float o = b2[t];
        for (int k = 0; k < 64; ++k) o += hid[k] * W2[k * N_TARGETS + t];
        out[g * N_TARGETS + t] = o;
    }
}

extern "C" void kernel_launch(void* const* d_in, const int* in_sizes, int n_in,
                              void* d_out, int out_size, void* d_ws, size_t ws_size,
                              hipStream_t stream) {
    const float* x    = (const float*)d_in[0];
    const int*   ei   = (const int*)d_in[1];
    const int*   batch= (const int*)d_in[2];
    const float* W    = (const float*)d_in[3];
    const float* a_s  = (const float*)d_in[4];
    const float* a_d  = (const float*)d_in[5];
    const float* bias = (const float*)d_in[6];
    const float* W1   = (const float*)d_in[7];
    const float* b1   = (const float*)d_in[8];
    const float* W2   = (const float*)d_in[9];
    const float* b2   = (const float*)d_in[10];
    float* out = (float*)d_out;
    const int* srcp = ei;
    const int* dstp = ei + N_EDGES;

    char* p = (char*)d_ws;
    float* bufA = (float*)p; p += (size_t)N_NODES * D * 4;      // 51.2 MB
    float* bufB = (float*)p; p += (size_t)N_NODES * D * 4;      // 51.2 MB
    u16* hb     = (u16*)p;   p += (size_t)N_NODES * D * 2;      // 25.6 MB
    int* csrf   = (int*)p;   p += (size_t)N_NODES * CSR_W * 4;  // 25.6 MB
    float* als  = (float*)p; p += (size_t)N_NODES * 4;
    float* ald  = (float*)p; p += (size_t)N_NODES * 4;
    int* deg    = (int*)p;   p += (size_t)N_NODES * 4;
    int* gstart = (int*)p;   p += 132 * 4;
    float* gpool = (float*)p; p += N_GRAPHS * D * 4;

    hipMemsetAsync(deg, 0, N_NODES * 4, stream);
    hipMemsetAsync(gpool, 0, N_GRAPHS * D * 4, stream);

    int eb = (E_TOT + 255) / 256;
    build_kernel<<<eb, 256, 0, stream>>>(srcp, dstp, deg, csrf);
    bounds_kernel<<<1, 256, 0, stream>>>(batch, gstart);

    const float* cur = x;
    float* outs[3] = {bufA, bufB, bufA};
    for (int l = 0; l < N_LAYERS; ++l) {
        gemm_kernel<<<(N_NODES + 127) / 128, 512, 0, stream>>>(
            cur, W + (size_t)l * D * D, a_s + (size_t)l * D, a_d + (size_t)l * D,
            hb, als, ald);
        edge_kernel<<<(N_NODES * 64 + 255) / 256, 256, 0, stream>>>(
            hb, als, ald, deg, csrf, bias + (size_t)l * D, srcp, dstp, outs[l]);
        cur = outs[l];
    }
    pool_kernel<<<N_GRAPHS * 8, 128, 0, stream>>>(cur, gstart, gpool);
    readout_kernel<<<N_GRAPHS, 64, 0, stream>>>(gpool, W1, b1, W2, b2, out);
}

// Round 7
// 605.367 us; speedup vs baseline: 1.8883x; 1.1746x over previous
//
#include <hip/hip_runtime.h>
#include <math.h>

#define N_NODES 100000
#define N_EDGES 1600000
#define D 128
#define N_LAYERS 3
#define N_GRAPHS 128
#define N_TARGETS 10
#define NEG_SLOPE 0.2f
#define E_TOT (N_EDGES + N_NODES)
#define CSR_W 64   /* fixed-width CSR rows; deg>64 handled by fallback scan */

typedef unsigned int u32;
typedef unsigned short u16;
typedef __attribute__((ext_vector_type(8))) short bf16x8;
typedef __attribute__((ext_vector_type(4))) float f32x4;

__device__ __forceinline__ float bf2f(u16 b) {
    u32 u = ((u32)b) << 16;
    return __uint_as_float(u);
}
__device__ __forceinline__ u16 f2bf(float f) {  // round-to-nearest-even
    u32 u = __float_as_uint(f);
    u32 r = (u + 0x7fffu + ((u >> 16) & 1u)) >> 16;
    return (u16)r;
}

// ---------------- CSR build: ONE kernel, fixed-width rows ----------------
__global__ void build_kernel(const int* __restrict__ src, const int* __restrict__ dst,
                             int* __restrict__ deg, int* __restrict__ csrf) {
    int i = blockIdx.x * blockDim.x + threadIdx.x;
    if (i >= E_TOT) return;
    int s, d;
    if (i < N_EDGES) { s = src[i]; d = dst[i]; } else { s = d = i - N_EDGES; }
    int r = atomicAdd(&deg[d], 1);
    if (r < CSR_W) csrf[d * CSR_W + r] = s;
}

// ---------------- MFMA GEMM: Hb(bf16) = X @ W, als = H.a_src, ald = H.a_dst -------
// 256 threads = 4 waves; BM=128, N=K=128. Waves own 32 rows each (2 row-tiles).
// A-operand = W^T frag (A[c][k]), B-operand = X frag (B[k][r]) so D[c][r]=H[r][c]:
// lane (r16=lane&15, g=lane>>4) holds H[row, ct*16+g*4+j] -> 8B packed stores.
__global__ __launch_bounds__(256) void gemm_kernel(
        const float* __restrict__ X, const float* __restrict__ Wl,
        const float* __restrict__ asr, const float* __restrict__ ads,
        u16* __restrict__ Hb, float* __restrict__ als, float* __restrict__ ald) {
    __shared__ u16 xa[128][136];   // X tile, bf16, row-major [row][k]
    __shared__ u16 wt[128][136];   // W^T,   bf16, [col][k]
    int tid = threadIdx.x;
    int row0 = blockIdx.x * 128;

    // stage X -> bf16 (coalesced float4 reads, 8B LDS writes)
    #pragma unroll
    for (int i = 0; i < 16; ++i) {
        int e = (i * 256 + tid) * 4;
        int r = e >> 7, c = e & 127;
        int row = row0 + r;
        float4 v = make_float4(0.f, 0.f, 0.f, 0.f);
        if (row < N_NODES) v = *(const float4*)&X[(size_t)row * D + c];
        u32 lo = (u32)f2bf(v.x) | ((u32)f2bf(v.y) << 16);
        u32 hi = (u32)f2bf(v.z) | ((u32)f2bf(v.w) << 16);
        *(uint2*)&xa[r][c] = make_uint2(lo, hi);
    }
    // stage W^T -> bf16 (coalesced reads, scattered b16 LDS writes; one-time)
    #pragma unroll
    for (int i = 0; i < 16; ++i) {
        int e = (i * 256 + tid) * 4;
        int k = e >> 7, c = e & 127;
        float4 v = *(const float4*)&Wl[e];
        wt[c + 0][k] = f2bf(v.x);
        wt[c + 1][k] = f2bf(v.y);
        wt[c + 2][k] = f2bf(v.z);
        wt[c + 3][k] = f2bf(v.w);
    }
    __syncthreads();

    int wv   = tid >> 6;
    int lane = tid & 63;
    int r16  = lane & 15;
    int g    = lane >> 4;      // 0..3
    int rbase = wv * 32;

    f32x4 acc[2][8];
    #pragma unroll
    for (int rt = 0; rt < 2; ++rt)
        #pragma unroll
        for (int ct = 0; ct < 8; ++ct) acc[rt][ct] = (f32x4){0.f, 0.f, 0.f, 0.f};

    #pragma unroll
    for (int kk = 0; kk < 4; ++kk) {
        int k0 = kk * 32 + g * 8;
        bf16x8 bx0 = *(const bf16x8*)&xa[rbase + r16][k0];
        bf16x8 bx1 = *(const bf16x8*)&xa[rbase + 16 + r16][k0];
        #pragma unroll
        for (int ct = 0; ct < 8; ++ct) {
            bf16x8 aw = *(const bf16x8*)&wt[ct * 16 + r16][k0];
            acc[0][ct] = __builtin_amdgcn_mfma_f32_16x16x32_bf16(aw, bx0, acc[0][ct], 0, 0, 0);
            acc[1][ct] = __builtin_amdgcn_mfma_f32_16x16x32_bf16(aw, bx1, acc[1][ct], 0, 0, 0);
        }
    }

    // epilogue: row-dots with a_src/a_dst + packed bf16 stores
    #pragma unroll
    for (int rt = 0; rt < 2; ++rt) {
        int row = row0 + rbase + rt * 16 + r16;
        float ps = 0.f, pd = 0.f;
        #pragma unroll
        for (int ct = 0; ct < 8; ++ct) {
            float4 av = *(const float4*)&asr[ct * 16 + g * 4];
            float4 dv = *(const float4*)&ads[ct * 16 + g * 4];
            f32x4 a = acc[rt][ct];
            ps += a[0] * av.x + a[1] * av.y + a[2] * av.z + a[3] * av.w;
            pd += a[0] * dv.x + a[1] * dv.y + a[2] * dv.z + a[3] * dv.w;
        }
        ps += __shfl_xor(ps, 16); ps += __shfl_xor(ps, 32);
        pd += __shfl_xor(pd, 16); pd += __shfl_xor(pd, 32);
        if (row < N_NODES) {
            #pragma unroll
            for (int ct = 0; ct < 8; ++ct) {
                f32x4 a = acc[rt][ct];
                u32 lo = (u32)f2bf(a[0]) | ((u32)f2bf(a[1]) << 16);
                u32 hi = (u32)f2bf(a[2]) | ((u32)f2bf(a[3]) << 16);
                *(uint2*)&Hb[(size_t)row * D + ct * 16 + g * 4] = make_uint2(lo, hi);
            }
            if (g == 0) { als[row] = ps; ald[row] = pd; }
        }
    }
}

// ---------------- Edge softmax + aggregate: one wave per dst node ----------------
__global__ __launch_bounds__(256) void edge_kernel(
        const u16* __restrict__ hb, const float* __restrict__ als,
        const float* __restrict__ ald, const int* __restrict__ deg_arr,
        const int* __restrict__ csrf, const float* __restrict__ bias,
        const int* __restrict__ esrc, const int* __restrict__ edst,
        float* __restrict__ out) {
    int gtid = blockIdx.x * blockDim.x + threadIdx.x;
    int node = gtid >> 6;
    int lane = threadIdx.x & 63;
    if (node >= N_NODES) return;
    int deg = deg_arr[node];
    float ad = ald[node];
    float accx = 0.f, accy = 0.f;
    const u16* hl = hb + lane * 2;

    if (deg <= CSR_W) {
        int sreg = 0;
        float v = -3.0e38f;
        if (lane < deg) {
            sreg = csrf[node * CSR_W + lane];
            float t = als[sreg] + ad;
            v = (t > 0.f) ? t : NEG_SLOPE * t;
        }
        float m = v;
        #pragma unroll
        for (int o = 1; o < 64; o <<= 1) m = fmaxf(m, __shfl_xor(m, o));
        float w = (lane < deg) ? __expf(v - m) : 0.f;
        float sum = w;
        #pragma unroll
        for (int o = 1; o < 64; o <<= 1) sum += __shfl_xor(sum, o);
        w *= 1.f / sum;

        int e = 0;
        for (; e + 8 <= deg; e += 8) {
            int s[8]; float wv[8]; ushort2 hv[8];
            #pragma unroll
            for (int k = 0; k < 8; ++k) { s[k] = __shfl(sreg, e + k); wv[k] = __shfl(w, e + k); }
            #pragma unroll
            for (int k = 0; k < 8; ++k) hv[k] = *(const ushort2*)(hl + (size_t)s[k] * D);
            #pragma unroll
            for (int k = 0; k < 8; ++k) {
                accx += wv[k] * bf2f(hv[k].x);
                accy += wv[k] * bf2f(hv[k].y);
            }
        }
        for (; e < deg; ++e) {
            int s0 = __shfl(sreg, e);
            float w0 = __shfl(w, e);
            ushort2 h0 = *(const ushort2*)(hl + (size_t)s0 * D);
            accx += w0 * bf2f(h0.x);
            accy += w0 * bf2f(h0.y);
        }
    } else {
        // overflow fallback (deg > CSR_W): scan the raw edge list.
        float lm = -3.0e38f;
        for (int j = lane; j < E_TOT; j += 64) {
            int d = (j < N_EDGES) ? edst[j] : (j - N_EDGES);
            if (d == node) {
                int s = (j < N_EDGES) ? esrc[j] : (j - N_EDGES);
                float t = als[s] + ad;
                t = (t > 0.f) ? t : NEG_SLOPE * t;
                lm = fmaxf(lm, t);
            }
        }
        #pragma unroll
        for (int o = 1; o < 64; o <<= 1) lm = fmaxf(lm, __shfl_xor(lm, o));
        float m = lm;
        float lsum = 0.f;
        for (int j = lane; j < E_TOT; j += 64) {
            int d = (j < N_EDGES) ? edst[j] : (j - N_EDGES);
            if (d == node) {
                int s = (j < N_EDGES) ? esrc[j] : (j - N_EDGES);
                float t = als[s] + ad;
                t = (t > 0.f) ? t : NEG_SLOPE * t;
                lsum += __expf(t - m);
            }
        }
        #pragma unroll
        for (int o = 1; o < 64; o <<= 1) lsum += __shfl_xor(lsum, o);
        float invden = 1.f / lsum;
        for (int base = 0; base < E_TOT; base += 64) {
            int j = base + lane;
            int d = -1;
            if (j < E_TOT) d = (j < N_EDGES) ? edst[j] : (j - N_EDGES);
            unsigned long long mask = __ballot(d == node);
            while (mask) {
                int b = __ffsll(mask) - 1;
                mask &= mask - 1;
                int jj = base + b;
                int s = (jj < N_EDGES) ? esrc[jj] : (jj - N_EDGES);
                float t = als[s] + ad;
                t = (t > 0.f) ? t : NEG_SLOPE * t;
                float w = __expf(t - m) * invden;
                ushort2 hv = *(const ushort2*)(hl + (size_t)s * D);
                accx += w * bf2f(hv.x);
                accy += w * bf2f(hv.y);
            }
        }
    }

    float2 bv = *(const float2*)(bias + lane * 2);
    *(float2*)(out + (size_t)node * D + lane * 2) = make_float2(accx + bv.x, accy + bv.y);
}

// ---------------- Pooling + readout ----------------
__global__ void bounds_kernel(const int* __restrict__ batch, int* __restrict__ gstart) {
    int g = blockIdx.x * blockDim.x + threadIdx.x;
    if (g > N_GRAPHS) return;
    if (g == N_GRAPHS) { gstart[g] = N_NODES; return; }
    int lo = 0, hi = N_NODES;
    while (lo < hi) { int mid = (lo + hi) >> 1; if (batch[mid] < g) lo = mid + 1; else hi = mid; }
    gstart[g] = lo;
}

__global__ void pool_kernel(const float* __restrict__ x, const int* __restrict__ gstart,
                            float* __restrict__ gpool) {
    int g = blockIdx.x >> 3, c = blockIdx.x & 7;
    int t = threadIdx.x;
    int beg = gstart[g], end = gstart[g + 1];
    float acc = 0.f;
    for (int i = beg + c; i < end; i += 8) acc += x[(size_t)i * D + t];
    atomicAdd(&gpool[g * D + t], acc);
}

__global__ void readout_kernel(const float* __restrict__ gpool,
                               const float* __restrict__ W1, const float* __restrict__ b1,
                               const float* __restrict__ W2, const float* __restrict__ b2,
                               float* __restrict__ out) {
    int g = blockIdx.x;
    int t = threadIdx.x;   // 64 threads
    __shared__ float hid[64];
    float a = b1[t];
    for (int k = 0; k < D; ++k) a += gpool[g * D + k] * W1[k * 64 + t];
    hid[t] = fmaxf(a, 0.f);
    __syncthreads();
    if (t < N_TARGETS) {
        float o = b2[t];
        for (int k = 0; k < 64; ++k) o += hid[k] * W2[k * N_TARGETS + t];
        out[g * N_TARGETS + t] = o;
    }
}

extern "C" void kernel_launch(void* const* d_in, const int* in_sizes, int n_in,
                              void* d_out, int out_size, void* d_ws, size_t ws_size,
                              hipStream_t stream) {
    const float* x    = (const float*)d_in[0];
    const int*   ei   = (const int*)d_in[1];
    const int*   batch= (const int*)d_in[2];
    const float* W    = (const float*)d_in[3];
    const float* a_s  = (const float*)d_in[4];
    const float* a_d  = (const float*)d_in[5];
    const float* bias = (const float*)d_in[6];
    const float* W1   = (const float*)d_in[7];
    const float* b1   = (const float*)d_in[8];
    const float* W2   = (const float*)d_in[9];
    const float* b2   = (const float*)d_in[10];
    float* out = (float*)d_out;
    const int* srcp = ei;
    const int* dstp = ei + N_EDGES;

    char* p = (char*)d_ws;
    float* bufA = (float*)p; p += (size_t)N_NODES * D * 4;      // 51.2 MB
    float* bufB = (float*)p; p += (size_t)N_NODES * D * 4;      // 51.2 MB
    u16* hb     = (u16*)p;   p += (size_t)N_NODES * D * 2;      // 25.6 MB
    int* csrf   = (int*)p;   p += (size_t)N_NODES * CSR_W * 4;  // 25.6 MB
    float* als  = (float*)p; p += (size_t)N_NODES * 4;
    float* ald  = (float*)p; p += (size_t)N_NODES * 4;
    int* deg    = (int*)p;   p += (size_t)N_NODES * 4;
    int* gstart = (int*)p;   p += 132 * 4;
    float* gpool = (float*)p; p += N_GRAPHS * D * 4;

    hipMemsetAsync(deg, 0, N_NODES * 4, stream);
    hipMemsetAsync(gpool, 0, N_GRAPHS * D * 4, stream);

    int eb = (E_TOT + 255) / 256;
    build_kernel<<<eb, 256, 0, stream>>>(srcp, dstp, deg, csrf);
    bounds_kernel<<<1, 256, 0, stream>>>(batch, gstart);

    const float* cur = x;
    float* outs[3] = {bufA, bufB, bufA};
    for (int l = 0; l < N_LAYERS; ++l) {
        gemm_kernel<<<(N_NODES + 127) / 128, 256, 0, stream>>>(
            cur, W + (size_t)l * D * D, a_s + (size_t)l * D, a_d + (size_t)l * D,
            hb, als, ald);
        edge_kernel<<<(N_NODES * 64 + 255) / 256, 256, 0, stream>>>(
            hb, als, ald, deg, csrf, bias + (size_t)l * D, srcp, dstp, outs[l]);
        cur = outs[l];
    }
    pool_kernel<<<N_GRAPHS * 8, 128, 0, stream>>>(cur, gstart, gpool);
    readout_kernel<<<N_GRAPHS, 64, 0, stream>>>(gpool, W1, b1, W2, b2, out);
}